// Round 5
// baseline (440.138 us; speedup 1.0000x reference)
//
#include <hip/hip_runtime.h>

// Multi-head VQ: inputs (16,2048,1024) f32, embeddings (4,64,256) f32.
// Out flat f32: quantized_st[33554432] | loss[1] | indices[131072 as float].
// Decomposition: lane = token; wave-PAIR owns 64 tokens x one head; the two
// waves split the 256-dim reduction 128/128 (matches numpy pairwise halves).
// e stays wave-uniform -> s_load feeding v_fma's SGPR operand.
// quantized_st written as q directly (|x+(q-x) - q| ~ 1e-6 << 1.26 thr).
// loss accumulated as min distance (== ||q-x||^2 within ~1e-6 rel).

#define HH   4
#define KK   64
#define HD   256
#define DD   1024
#define NTOK 32768
#define NDQ  33554432ull
#define NPART 2048   // 2 wave-pairs per block * 1024 blocks

__global__ void vq_cbq(const float* __restrict__ emb, float* __restrict__ cbq)
{
    const int t = threadIdx.x;               // one per (h,k)
    const float* e = emb + (size_t)t * HD;
    float s = 0.f;
    {
        #pragma clang fp contract(off)
        for (int d = 0; d < HD; ++d) {
            float p = e[d] * e[d];
            s = s + p;
        }
    }
    cbq[t] = s;
}

__global__ __launch_bounds__(256, 4) void vq_main(
    const float* __restrict__ x, const float* __restrict__ emb,
    const float* __restrict__ cbq, float* __restrict__ out,
    double* __restrict__ partial)
{
    __shared__ float accL[2][KK][64];   // [pair][k][lane] 32 KB
    __shared__ float isqB[2][64];
    __shared__ int   biL[2][64];

    const int h    = blockIdx.y;
    const int wv   = threadIdx.x >> 6;
    const int lane = threadIdx.x & 63;
    const int pair = wv >> 1;           // 0,1 : token group
    const int hf   = wv & 1;            // 0,1 : dim half
    const int tok  = blockIdx.x * 128 + pair * 64 + lane;

    const float* __restrict__ eh   = emb + (size_t)h * (KK * HD);
    const float* __restrict__ ehh  = eh + hf * 128;              // uniform
    const float* __restrict__ xrow = x + (size_t)tok * DD + (size_t)h * HD + hf * 128;
    const float* __restrict__ cbh  = cbq + h * KK;

    float acc[KK];
    #pragma unroll
    for (int k = 0; k < KK; ++k) acc[k] = 0.f;

    // numpy-pairwise 8-accumulator pattern over this wave's 128 dims.
    float r0=0.f,r1=0.f,r2=0.f,r3=0.f,r4=0.f,r5=0.f,r6=0.f,r7=0.f;

    float4 n0 = *(const float4*)(xrow + 0);
    float4 n1 = *(const float4*)(xrow + 4);
    float4 n2 = *(const float4*)(xrow + 8);
    float4 n3 = *(const float4*)(xrow + 12);

    for (int c = 0; c < 8; ++c) {        // 8 chunks x 16 dims = 128
        const float4 a0 = n0, a1 = n1, a2 = n2, a3 = n3;
        if (c < 7) {
            const float* p = xrow + (c + 1) * 16;
            n0 = *(const float4*)(p + 0);
            n1 = *(const float4*)(p + 4);
            n2 = *(const float4*)(p + 8);
            n3 = *(const float4*)(p + 12);
        }
        const float xv[16] = { a0.x,a0.y,a0.z,a0.w, a1.x,a1.y,a1.z,a1.w,
                               a2.x,a2.y,a2.z,a2.w, a3.x,a3.y,a3.z,a3.w };
        const float* __restrict__ ec = ehh + c * 16;   // wave-uniform
        #pragma unroll
        for (int k = 0; k < KK; ++k) {
            const float* __restrict__ ek = ec + (size_t)k * HD;  // -> s_load
            float a = acc[k];
            #pragma unroll
            for (int j = 0; j < 16; ++j)
                a = __builtin_fmaf(ek[j], xv[j], a);
            acc[k] = a;
        }
        {
            #pragma clang fp contract(off)
            r0 = r0 + xv[0]*xv[0];   r1 = r1 + xv[1]*xv[1];
            r2 = r2 + xv[2]*xv[2];   r3 = r3 + xv[3]*xv[3];
            r4 = r4 + xv[4]*xv[4];   r5 = r5 + xv[5]*xv[5];
            r6 = r6 + xv[6]*xv[6];   r7 = r7 + xv[7]*xv[7];
            r0 = r0 + xv[8]*xv[8];   r1 = r1 + xv[9]*xv[9];
            r2 = r2 + xv[10]*xv[10]; r3 = r3 + xv[11]*xv[11];
            r4 = r4 + xv[12]*xv[12]; r5 = r5 + xv[13]*xv[13];
            r6 = r6 + xv[14]*xv[14]; r7 = r7 + xv[15]*xv[15];
        }
    }
    const float halfSq = ((r0 + r1) + (r2 + r3)) + ((r4 + r5) + (r6 + r7));

    if (hf == 1) {                      // publish partials (dims 128..255)
        #pragma unroll 8
        for (int k = 0; k < KK; ++k) accL[pair][k][lane] = acc[k];
        isqB[pair][lane] = halfSq;
    }
    __syncthreads();

    if (hf == 0) {
        const float isq = halfSq + isqB[pair][lane];   // halves in numpy order

        // combine dots + argmin; strict < keeps first index (np.argmin).
        float bv = 0.f; int bi = 0;
        #pragma unroll 8
        for (int k = 0; k < KK; ++k) {
            const float dot = acc[k] + accL[pair][k][lane];
            const float d = (isq + cbh[k]) - 2.0f * dot;
            if (k == 0) { bv = d; bi = 0; }
            else {
                const bool lt = d < bv;
                bv = lt ? d : bv;
                bi = lt ? k : bi;
            }
        }
        biL[pair][lane] = bi;
        out[NDQ + 1 + (size_t)tok * HH + h] = (float)bi;

        float loss = bv;                 // min dist == ||q-x||^2 (~1e-6 rel)
        #pragma unroll
        for (int m = 1; m < 64; m <<= 1) loss += __shfl_xor(loss, m);
        if (lane == 0) {
            const int wgid = (blockIdx.y * gridDim.x + blockIdx.x) * 2 + pair;
            partial[wgid] = (double)loss;
        }
    }
    __syncthreads();

    // Epilogue: pair's 64 q-rows split 32/32 between its two waves.
    const int tbase = blockIdx.x * 128 + pair * 64 + hf * 32;
    for (int t = 0; t < 32; ++t) {
        const int kst = biL[pair][hf * 32 + t];
        const float4 q4 = *(const float4*)(eh + (size_t)kst * HD + lane * 4);
        *(float4*)(out + (size_t)(tbase + t) * DD + (size_t)h * HD + lane * 4) = q4;
    }
}

__global__ void vq_finalize(const double* __restrict__ partial,
                            float* __restrict__ out)
{
    const int lane = threadIdx.x & 63;
    double s = 0.0;
    for (int i = 0; i < NPART / 64; ++i) s += partial[i * 64 + lane];
    #pragma unroll
    for (int m = 1; m < 64; m <<= 1) s += __shfl_xor(s, m);
    if (lane == 0) {
        const float mv = (float)(s / (double)NDQ);
        out[NDQ] = mv + 0.5f * mv;   // q_latent + 0.5*e_latent (equal values)
    }
}

extern "C" void kernel_launch(void* const* d_in, const int* in_sizes, int n_in,
                              void* d_out, int out_size, void* d_ws, size_t ws_size,
                              hipStream_t stream)
{
    const float* x   = (const float*)d_in[0];
    const float* emb = (const float*)d_in[1];
    float* out = (float*)d_out;
    double* partial = (double*)d_ws;                       // 2048 doubles
    float*  cbq     = (float*)((char*)d_ws + NPART * 8);   // 256 floats

    vq_cbq<<<1, dim3(256), 0, stream>>>(emb, cbq);
    vq_main<<<dim3(NTOK / 128, HH), dim3(256), 0, stream>>>(x, emb, cbq, out, partial);
    vq_finalize<<<1, dim3(64), 0, stream>>>(partial, out);
}

// Round 6
// 191.125 us; speedup vs baseline: 2.3029x; 2.3029x over previous
//
#include <hip/hip_runtime.h>

// Multi-head VQ: inputs (16,2048,1024) f32, embeddings (4,64,256) f32.
// Out flat f32: quantized_st[33554432] | loss[1] | indices[131072 as float].
// Block = 64 tokens x 1 head. 4 waves split the 64 codes (16 each) so the
// per-lane accumulator tile is acc[16] (register-resident, no scratch).
// lane = token; x streamed in 16-dim chunks (R3's bit-exact order);
// e wave-uniform -> s_load feeding v_fma's SGPR operand.
// quantized_st written as q directly (|x+(q-x)-q| ~1e-6 << 1.26 thr);
// loss = min distance (== ||q-x||^2 within ~1e-6 rel).

#define HH   4
#define KK   64
#define HD   256
#define DD   1024
#define NTOK 32768
#define NDQ  33554432ull
#define NPART 2048   // one partial per block (512 groups x 4 heads)

__global__ void vq_cbq(const float* __restrict__ emb, float* __restrict__ cbq)
{
    const int t = threadIdx.x;               // one per (h,k)
    const float* e = emb + (size_t)t * HD;
    float s = 0.f;
    {
        #pragma clang fp contract(off)
        for (int d = 0; d < HD; ++d) {
            float p = e[d] * e[d];
            s = s + p;
        }
    }
    cbq[t] = s;
}

__global__ __launch_bounds__(256, 4) void vq_main(
    const float* __restrict__ x, const float* __restrict__ emb,
    const float* __restrict__ cbq, float* __restrict__ out,
    double* __restrict__ partial)
{
    __shared__ float vals[4][64];
    __shared__ int   idxs[4][64];

    const int h    = blockIdx.y;
    const int wv   = __builtin_amdgcn_readfirstlane(threadIdx.x >> 6);
    const int lane = threadIdx.x & 63;
    const int tok  = blockIdx.x * 64 + lane;

    const float* __restrict__ eh   = emb + (size_t)h * (KK * HD);
    const float* __restrict__ ew   = eh + (size_t)wv * 16 * HD;   // wave's codes
    const float* __restrict__ xrow = x + (size_t)tok * DD + (size_t)h * HD;
    const float* __restrict__ cbh  = cbq + h * KK + wv * 16;

    float acc[16];
    #pragma unroll
    for (int k = 0; k < 16; ++k) acc[k] = 0.f;

    // numpy-pairwise input_sq: r[d&7] += x[d]^2, d ascending; halves at 128.
    float r0=0.f,r1=0.f,r2=0.f,r3=0.f,r4=0.f,r5=0.f,r6=0.f,r7=0.f;
    float halfA = 0.f;

    float4 n0 = *(const float4*)(xrow + 0);
    float4 n1 = *(const float4*)(xrow + 4);
    float4 n2 = *(const float4*)(xrow + 8);
    float4 n3 = *(const float4*)(xrow + 12);

    for (int c = 0; c < 16; ++c) {       // 16 chunks x 16 dims = 256
        const float4 a0 = n0, a1 = n1, a2 = n2, a3 = n3;
        if (c < 15) {
            const float* p = xrow + (c + 1) * 16;
            n0 = *(const float4*)(p + 0);
            n1 = *(const float4*)(p + 4);
            n2 = *(const float4*)(p + 8);
            n3 = *(const float4*)(p + 12);
        }
        const float xv[16] = { a0.x,a0.y,a0.z,a0.w, a1.x,a1.y,a1.z,a1.w,
                               a2.x,a2.y,a2.z,a2.w, a3.x,a3.y,a3.z,a3.w };
        #pragma unroll
        for (int k = 0; k < 16; ++k) {
            const float* __restrict__ ek = ew + (size_t)k * HD + c * 16; // uniform
            float a = acc[k];
            #pragma unroll
            for (int j = 0; j < 16; ++j)
                a = __builtin_fmaf(ek[j], xv[j], a);
            acc[k] = a;
        }
        {
            #pragma clang fp contract(off)
            r0 = r0 + xv[0]*xv[0];   r1 = r1 + xv[1]*xv[1];
            r2 = r2 + xv[2]*xv[2];   r3 = r3 + xv[3]*xv[3];
            r4 = r4 + xv[4]*xv[4];   r5 = r5 + xv[5]*xv[5];
            r6 = r6 + xv[6]*xv[6];   r7 = r7 + xv[7]*xv[7];
            r0 = r0 + xv[8]*xv[8];   r1 = r1 + xv[9]*xv[9];
            r2 = r2 + xv[10]*xv[10]; r3 = r3 + xv[11]*xv[11];
            r4 = r4 + xv[12]*xv[12]; r5 = r5 + xv[13]*xv[13];
            r6 = r6 + xv[14]*xv[14]; r7 = r7 + xv[15]*xv[15];
        }
        if (c == 7) {   // close first 128-dim block, numpy combine order
            halfA = ((r0 + r1) + (r2 + r3)) + ((r4 + r5) + (r6 + r7));
            r0=r1=r2=r3=r4=r5=r6=r7=0.f;
        }
    }
    const float halfB = ((r0 + r1) + (r2 + r3)) + ((r4 + r5) + (r6 + r7));
    const float isq = halfA + halfB;

    // This wave's 16 codes: dist = (isq + cbq[k]) - 2*dot; strict < argmin.
    float bv = (isq + cbh[0]) - 2.0f * acc[0];
    int   bi = 0;
    #pragma unroll
    for (int k = 1; k < 16; ++k) {
        const float d = (isq + cbh[k]) - 2.0f * acc[k];
        const bool lt = d < bv;
        bv = lt ? d : bv;
        bi = lt ? k : bi;
    }
    vals[wv][lane] = bv;
    idxs[wv][lane] = wv * 16 + bi;
    __syncthreads();

    // Cross-wave combine in wave order (strict < => global first-index).
    if (wv == 0) {
        float f  = vals[0][lane];
        int   fi = idxs[0][lane];
        #pragma unroll
        for (int w = 1; w < 4; ++w) {
            const float v  = vals[w][lane];
            const int   vi = idxs[w][lane];
            const bool lt = v < f;
            f  = lt ? v  : f;
            fi = lt ? vi : fi;
        }
        out[NDQ + 1 + (size_t)tok * HH + h] = (float)fi;
        idxs[0][lane] = fi;              // publish for epilogue

        float loss = f;                  // min dist == ||q-x||^2 (~1e-6 rel)
        #pragma unroll
        for (int m = 1; m < 64; m <<= 1) loss += __shfl_xor(loss, m);
        if (lane == 0)
            partial[(size_t)blockIdx.y * gridDim.x + blockIdx.x] = (double)loss;
    }
    __syncthreads();

    // Epilogue: 64 q-rows split 16/wave; codebook row gather is L2-resident.
    for (int t = 0; t < 16; ++t) {
        const int row = wv * 16 + t;
        const int kst = idxs[0][row];    // uniform per wave -> broadcast
        const float4 q4 = *(const float4*)(eh + (size_t)kst * HD + lane * 4);
        *(float4*)(out + (size_t)(blockIdx.x * 64 + row) * DD
                       + (size_t)h * HD + lane * 4) = q4;
    }
}

__global__ void vq_finalize(const double* __restrict__ partial,
                            float* __restrict__ out)
{
    const int lane = threadIdx.x & 63;
    double s = 0.0;
    for (int i = 0; i < NPART / 64; ++i) s += partial[i * 64 + lane];
    #pragma unroll
    for (int m = 1; m < 64; m <<= 1) s += __shfl_xor(s, m);
    if (lane == 0) {
        const float mv = (float)(s / (double)NDQ);
        out[NDQ] = mv + 0.5f * mv;   // q_latent + 0.5*e_latent (equal values)
    }
}

extern "C" void kernel_launch(void* const* d_in, const int* in_sizes, int n_in,
                              void* d_out, int out_size, void* d_ws, size_t ws_size,
                              hipStream_t stream)
{
    const float* x   = (const float*)d_in[0];
    const float* emb = (const float*)d_in[1];
    float* out = (float*)d_out;
    double* partial = (double*)d_ws;                       // 2048 doubles
    float*  cbq     = (float*)((char*)d_ws + NPART * 8);   // 256 floats

    vq_cbq<<<1, dim3(256), 0, stream>>>(emb, cbq);
    vq_main<<<dim3(NTOK / 64, HH), dim3(256), 0, stream>>>(x, emb, cbq, out, partial);
    vq_finalize<<<1, dim3(64), 0, stream>>>(partial, out);
}